// Round 4
// baseline (315.410 us; speedup 1.0000x reference)
//
#include <hip/hip_runtime.h>
#include <math.h>

#define M_GRID 128
#define J_FEAT 80
#define NNET   160   // NBASE*J_FEAT
#define HDIM   256

typedef __attribute__((ext_vector_type(8))) short v8s;  // 8 bf16
typedef __attribute__((ext_vector_type(4))) float f4;   // MFMA accum

__device__ __forceinline__ unsigned short f2bf(float f) {
    unsigned u = __float_as_uint(f);
    u += 0x7fffu + ((u >> 16) & 1u);   // round-to-nearest-even
    return (unsigned short)(u >> 16);
}

__device__ __forceinline__ float selu_f(float x) {
    const float SC = 1.0507009873554805f;
    const float AL = 1.6732632423543772f;
    return x > 0.f ? SC * x : SC * AL * (__expf(x) - 1.f);
}

// One workgroup per network n. 8 waves, role-split:
//   waves 0-3 = consumers: rows (c*16..c*16+15) [tile0] and (64+c*16..) [tile1],
//               acc[2][16] f4 in AGPRs, A-fragments in VGPRs, all MFMA.
//   waves 4-7 = producers: stream W via 32-column "eighths" (16 KB bf16 tiles,
//               double-buffered LDS), transposed+cvt in registers, issued TWO
//               eighths ahead (64 loads in flight/thread) so HBM latency hides
//               under barriers/MFMA (T14). One barrier per eighth.
// LDS 64 KB: wbuf 2x16 KB @0, scr 4x8 KB @32768 (per-consumer C->A transpose;
// also input-layer handoff of rows 64-127 from producers to consumers).
__attribute__((amdgpu_flat_work_group_size(512, 512), amdgpu_waves_per_eu(1, 2)))
__global__ void basis_kernel(const float* __restrict__ t,
                             const float* __restrict__ W_in,
                             const float* __restrict__ b_in,
                             const float* __restrict__ W_h,
                             const float* __restrict__ b_h,
                             const float* __restrict__ W_out,
                             const float* __restrict__ b_out,
                             const float* __restrict__ ln_a,
                             const float* __restrict__ ln_b,
                             float* __restrict__ basesT)   // [M][NNET]
{
    __shared__ __align__(16) unsigned char lds[65536];
    const int n    = blockIdx.x;
    const int tid  = threadIdx.x;
    const int l    = tid & 63;
    const int wv   = tid >> 6;
    const int lr   = l & 15;
    const int g    = l >> 4;
    const bool cons = (wv < 4);
    const int  c    = wv & 3;
    const int  mrow = (c << 4) + lr + ((wv >> 2) << 6);  // cons: c*16+lr, prod: 64+c*16+lr

    unsigned char* const scr = lds + 32768 + c * 8192;

    // ---------------- input layer (all waves, own 16 rows, A-layout) ----------------
    const float tval = t[mrow];
    v8s af0[8];
    {
        float zz[8][8];
        const float* wi = W_in + (size_t)n * HDIM;
        const float* bi = b_in + (size_t)n * HDIM;
        #pragma unroll
        for (int kt = 0; kt < 8; ++kt) {
            const int h0 = kt * 32 + g * 8;
            #pragma unroll
            for (int i = 0; i < 8; ++i)
                zz[kt][i] = tval * wi[h0 + i] + bi[h0 + i];
        }
        float s = 0.f, q = 0.f;
        #pragma unroll
        for (int kt = 0; kt < 8; ++kt)
            #pragma unroll
            for (int i = 0; i < 8; ++i) { float v = zz[kt][i]; s += v; q += v * v; }
        s += __shfl_xor(s, 16); q += __shfl_xor(q, 16);
        s += __shfl_xor(s, 32); q += __shfl_xor(q, 32);
        const float mean = s * (1.f / 256.f);
        const float var  = (q - s * s * (1.f / 256.f)) * (1.f / 255.f); // unbiased
        const float inv  = 1.f / (sqrtf(var) + 1e-6f);                  // eps on std
        const float* la = ln_a + (size_t)n * HDIM;
        const float* lb = ln_b + (size_t)n * HDIM;
        #pragma unroll
        for (int kt = 0; kt < 8; ++kt) {
            const int h0 = kt * 32 + g * 8;
            v8s a;
            #pragma unroll
            for (int i = 0; i < 8; ++i) {
                float v   = zz[kt][i];
                float lnv = (v - mean) * inv * la[h0 + i] + lb[h0 + i];
                a[i] = (short)f2bf(selu_f(v + lnv));
            }
            af0[kt] = a;
        }
    }
    if (!cons) {   // hand rows 64-127 to consumer c via scr region c
        #pragma unroll
        for (int kt = 0; kt < 8; ++kt) {
            const int byte = (lr * 512 + (kt * 32 + g * 8) * 2) ^ (lr << 5);
            *(v8s*)(scr + byte) = af0[kt];
        }
    }
    __syncthreads();

    v8s afA[8], afB[8];
    if (cons) {
        #pragma unroll
        for (int kt = 0; kt < 8; ++kt) {
            afA[kt] = af0[kt];
            const int byte = (lr * 512 + (kt * 32 + g * 8) * 2) ^ (lr << 5);
            afB[kt] = *(const v8s*)(scr + byte);
        }
    }

    // ---------------- producer staging helpers ----------------
    const int jq = tid & 31;          // column within eighth
    const int ko = (tid >> 5) & 7;    // 32-wide k-chunk
    float fA[32], fB[32];

    auto issueL = [&](float (&f)[32], int eg) {   // eg = global eighth 0..23
        const int Lx  = eg >> 3;
        const int elx = eg & 7;
        const float* src = W_h + ((size_t)(Lx * NNET + n) << 16)
                         + (size_t)ko * (32 * 256) + elx * 32 + jq;
        #pragma unroll
        for (int i = 0; i < 32; ++i) f[i] = src[(size_t)i * 256];
    };
    auto stageL = [&](float (&f)[32], int buf) {  // cvt + transposed LDS write
        const int swz = ((((jq & 15) << 1) | (jq >> 4)) << 4);
        #pragma unroll
        for (int p = 0; p < 4; ++p) {
            v8s pk;
            #pragma unroll
            for (int i = 0; i < 8; ++i) pk[i] = (short)f2bf(f[p * 8 + i]);
            const int byte = buf * 16384 + jq * 512 + (ko * 32 + p * 8) * 2;
            *(v8s*)(lds + (byte ^ swz)) = pk;
        }
    };

    if (!cons) { issueL(fA, 0); issueL(fB, 1); }   // 2-deep prologue

    f4 acc[2][16];

    #pragma unroll 1
    for (int L = 0; L < 3; ++L) {
        const f4 zero = {0.f, 0.f, 0.f, 0.f};
        #pragma unroll
        for (int tt = 0; tt < 2; ++tt)
            #pragma unroll
            for (int ctg = 0; ctg < 16; ++ctg) {
                acc[tt][ctg] = zero;
                asm volatile("" : "+a"(acc[tt][ctg]));  // pin to AGPR side
            }

        #pragma unroll
        for (int ep = 0; ep < 4; ++ep) {
            const int eg0 = L * 8 + ep * 2;
            if (!cons) { stageL(fA, 0); if (eg0 + 2 < 24) issueL(fA, eg0 + 2); }
            __syncthreads();
            if (cons) {
                #pragma unroll
                for (int kk = 0; kk < 8; ++kk)
                    #pragma unroll
                    for (int ctl = 0; ctl < 2; ++ctl) {
                        const int swz  = (((lr << 1) | ctl) << 4);
                        const int byte = (ctl * 16 + lr) * 512 + (kk * 32 + g * 8) * 2;
                        const v8s bf   = *(const v8s*)(lds + (byte ^ swz));
                        const int ctg  = ep * 4 + ctl;
                        acc[0][ctg] = __builtin_amdgcn_mfma_f32_16x16x32_bf16(afA[kk], bf, acc[0][ctg], 0, 0, 0);
                        acc[1][ctg] = __builtin_amdgcn_mfma_f32_16x16x32_bf16(afB[kk], bf, acc[1][ctg], 0, 0, 0);
                    }
            }
            if (!cons) { stageL(fB, 1); if (eg0 + 3 < 24) issueL(fB, eg0 + 3); }
            __syncthreads();
            if (cons) {
                #pragma unroll
                for (int kk = 0; kk < 8; ++kk)
                    #pragma unroll
                    for (int ctl = 0; ctl < 2; ++ctl) {
                        const int swz  = (((lr << 1) | ctl) << 4);
                        const int byte = 16384 + (ctl * 16 + lr) * 512 + (kk * 32 + g * 8) * 2;
                        const v8s bf   = *(const v8s*)(lds + (byte ^ swz));
                        const int ctg  = ep * 4 + 2 + ctl;
                        acc[0][ctg] = __builtin_amdgcn_mfma_f32_16x16x32_bf16(afA[kk], bf, acc[0][ctg], 0, 0, 0);
                        acc[1][ctg] = __builtin_amdgcn_mfma_f32_16x16x32_bf16(afB[kk], bf, acc[1][ctg], 0, 0, 0);
                    }
            }
        }

        // ---------------- consumer epilogue ----------------
        if (cons) {
            const float* bh = b_h  + ((size_t)L * NNET + n) * HDIM;
            const float* la = ln_a + ((size_t)(L + 1) * NNET + n) * HDIM;
            const float* lb = ln_b + ((size_t)(L + 1) * NNET + n) * HDIM;
            if (L < 2) {
                #pragma unroll
                for (int tt = 0; tt < 2; ++tt) {
                    float sums[4] = {0,0,0,0}, sqs[4] = {0,0,0,0};
                    #pragma unroll
                    for (int ctg = 0; ctg < 16; ++ctg) {
                        const float bias = bh[ctg * 16 + lr];
                        #pragma unroll
                        for (int r = 0; r < 4; ++r) {
                            float v = acc[tt][ctg][r] + bias;
                            acc[tt][ctg][r] = v;
                            sums[r] += v; sqs[r] += v * v;
                        }
                    }
                    #pragma unroll
                    for (int r = 0; r < 4; ++r)
                        #pragma unroll
                        for (int m = 1; m <= 8; m <<= 1) {
                            sums[r] += __shfl_xor(sums[r], m);
                            sqs[r]  += __shfl_xor(sqs[r],  m);
                        }
                    float mean[4], inv[4];
                    #pragma unroll
                    for (int r = 0; r < 4; ++r) {
                        mean[r] = sums[r] * (1.f / 256.f);
                        float var = (sqs[r] - sums[r] * sums[r] * (1.f / 256.f)) * (1.f / 255.f);
                        inv[r] = 1.f / (sqrtf(var) + 1e-6f);
                    }
                    #pragma unroll
                    for (int ctg = 0; ctg < 16; ++ctg) {
                        const float a_ = la[ctg * 16 + lr], b_ = lb[ctg * 16 + lr];
                        #pragma unroll
                        for (int r = 0; r < 4; ++r) {
                            float v  = acc[tt][ctg][r];
                            float sv = selu_f(v + (v - mean[r]) * inv[r] * a_ + b_);
                            const int row  = 4 * g + r;
                            const int byte = (row * 512 + (ctg * 16 + lr) * 2) ^ (row << 5);
                            *(unsigned short*)(scr + byte) = f2bf(sv);
                        }
                    }
                    #pragma unroll
                    for (int kt = 0; kt < 8; ++kt) {
                        const int byte = (lr * 512 + (kt * 32 + g * 8) * 2) ^ (lr << 5);
                        if (tt == 0) afA[kt] = *(const v8s*)(scr + byte);
                        else         afB[kt] = *(const v8s*)(scr + byte);
                    }
                }
            } else {
                const float* wo = W_out + (size_t)n * HDIM;
                const float bo  = b_out[n];
                #pragma unroll
                for (int tt = 0; tt < 2; ++tt) {
                    float sums[4] = {0,0,0,0}, sqs[4] = {0,0,0,0};
                    #pragma unroll
                    for (int ctg = 0; ctg < 16; ++ctg) {
                        const float bias = bh[ctg * 16 + lr];
                        #pragma unroll
                        for (int r = 0; r < 4; ++r) {
                            float v = acc[tt][ctg][r] + bias;
                            acc[tt][ctg][r] = v;
                            sums[r] += v; sqs[r] += v * v;
                        }
                    }
                    #pragma unroll
                    for (int r = 0; r < 4; ++r)
                        #pragma unroll
                        for (int m = 1; m <= 8; m <<= 1) {
                            sums[r] += __shfl_xor(sums[r], m);
                            sqs[r]  += __shfl_xor(sqs[r],  m);
                        }
                    float mean[4], inv[4];
                    #pragma unroll
                    for (int r = 0; r < 4; ++r) {
                        mean[r] = sums[r] * (1.f / 256.f);
                        float var = (sqs[r] - sums[r] * sums[r] * (1.f / 256.f)) * (1.f / 255.f);
                        inv[r] = 1.f / (sqrtf(var) + 1e-6f);
                    }
                    float ps[4] = {0,0,0,0};
                    #pragma unroll
                    for (int ctg = 0; ctg < 16; ++ctg) {
                        const float a_ = la[ctg * 16 + lr], b_ = lb[ctg * 16 + lr];
                        const float w_ = wo[ctg * 16 + lr];
                        #pragma unroll
                        for (int r = 0; r < 4; ++r) {
                            float v  = acc[tt][ctg][r];
                            float sv = selu_f(v + (v - mean[r]) * inv[r] * a_ + b_);
                            ps[r] += sv * w_;
                        }
                    }
                    #pragma unroll
                    for (int r = 0; r < 4; ++r)
                        #pragma unroll
                        for (int m = 1; m <= 8; m <<= 1)
                            ps[r] += __shfl_xor(ps[r], m);
                    const int rbase = (tt == 0 ? c * 16 : 64 + c * 16);
                    #pragma unroll
                    for (int r = 0; r < 4; ++r)
                        if (lr == r)
                            basesT[(size_t)(rbase + 4 * g + r) * NNET + n] = ps[r] + bo;
                }
            }
        }
    }
}

// score[b, jk] = sum_m x[b,m,jk>>1] * basesT[m][jk] * w[m]
__launch_bounds__(256)
__global__ void score_kernel(const float* __restrict__ x,
                             const float* __restrict__ t,
                             const float* __restrict__ basesT,
                             float* __restrict__ out)
{
    __shared__ float c_lds[M_GRID * 32];
    const int jt  = blockIdx.x;   // 0..4
    const int bt  = blockIdx.y;   // 0..255
    const int tid = threadIdx.x;

    for (int i = tid; i < M_GRID * 32; i += 256) {
        const int m  = i >> 5;
        const int jl = i & 31;
        const float tp = t[m == M_GRID - 1 ? M_GRID - 1 : m + 1];
        const float tm = t[m == 0 ? 0 : m - 1];
        c_lds[i] = basesT[(size_t)m * NNET + jt * 32 + jl] * 0.5f * (tp - tm);
    }
    __syncthreads();

    const int jj = tid & 31;
    const int bs = tid >> 5;
    const int jk = jt * 32 + jj;
    const int b  = bt * 8 + bs;
    const float* xp = x + (size_t)b * (M_GRID * J_FEAT) + (jk >> 1);
    float acc = 0.f;
    #pragma unroll 8
    for (int m = 0; m < M_GRID; ++m)
        acc += xp[(size_t)m * J_FEAT] * c_lds[m * 32 + jj];
    out[(size_t)b * NNET + jk] = acc;
}

extern "C" void kernel_launch(void* const* d_in, const int* in_sizes, int n_in,
                              void* d_out, int out_size, void* d_ws, size_t ws_size,
                              hipStream_t stream)
{
    const float* x     = (const float*)d_in[0];
    const float* t     = (const float*)d_in[1];
    const float* W_in  = (const float*)d_in[2];
    const float* b_in  = (const float*)d_in[3];
    const float* W_h   = (const float*)d_in[4];
    const float* b_h   = (const float*)d_in[5];
    const float* W_out = (const float*)d_in[6];
    const float* b_out = (const float*)d_in[7];
    const float* ln_a  = (const float*)d_in[8];
    const float* ln_b  = (const float*)d_in[9];
    float* basesT = (float*)d_ws;   // 128*160*4 = 80 KiB

    basis_kernel<<<dim3(NNET), dim3(512), 0, stream>>>(
        t, W_in, b_in, W_h, b_h, W_out, b_out, ln_a, ln_b, basesT);
    score_kernel<<<dim3(5, 256), dim3(256), 0, stream>>>(
        x, t, basesT, (float*)d_out);
}

// Round 5
// 149.056 us; speedup vs baseline: 2.1161x; 2.1161x over previous
//
#include <hip/hip_runtime.h>
#include <math.h>

#define M_GRID 128
#define J_FEAT 80
#define NNET   160   // NBASE*J_FEAT
#define HDIM   256

typedef __attribute__((ext_vector_type(8))) short v8s;  // 8 bf16
typedef __attribute__((ext_vector_type(4))) float f4;   // MFMA accum

__device__ __forceinline__ unsigned short f2bf(float f) {
    unsigned u = __float_as_uint(f);
    u += 0x7fffu + ((u >> 16) & 1u);   // round-to-nearest-even
    return (unsigned short)(u >> 16);
}

__device__ __forceinline__ float selu_f(float x) {
    const float SC = 1.0507009873554805f;
    const float AL = 1.6732632423543772f;
    return x > 0.f ? SC * x : SC * AL * (__expf(x) - 1.f);
}

// Raw barrier that does NOT drain vmcnt (keeps global_load_lds prefetch alive
// across phases). lgkmcnt(0) makes prior ds ops visible to the workgroup.
#define LGKM_BAR() do { asm volatile("s_waitcnt lgkmcnt(0)" ::: "memory"); \
                        __builtin_amdgcn_s_barrier(); } while (0)

// One workgroup per network n. 8 waves, ALL consumers (wave w owns rows
// 16w..16w+15; acc[16] f4 = 64 AGPRs pinned "+a"; A-fragments in VGPRs).
// Weight streaming: global_load_lds dwordx4 (zero register pressure) into
// fp32 sub-tiles [16 k][256 j] (16 KB, double-buffered, natural layout,
// perfectly coalesced). A cooperative LDS->LDS pass converts+transposes each
// sub-tile to XOR-swizzled bf16 [j][k] (double-buffered K=32 tiles) that MFMA
// reads as conflict-free-ish b128 fragments. In-loop sync = raw s_barrier +
// lgkmcnt only; counted vmcnt(2) keeps one 16 KB sub-tile in flight across
// barriers at all times (T3/T4).
// LDS 64 KB: fp32 bufs 2x16K @0, bf16 tiles 2x16K @32768; between layers the
// whole 64 KB is reused as per-wave C->A transpose scratch (barrier-protected).
__attribute__((amdgpu_flat_work_group_size(512, 512), amdgpu_waves_per_eu(1, 2)))
__global__ void basis_kernel(const float* __restrict__ t,
                             const float* __restrict__ W_in,
                             const float* __restrict__ b_in,
                             const float* __restrict__ W_h,
                             const float* __restrict__ b_h,
                             const float* __restrict__ W_out,
                             const float* __restrict__ b_out,
                             const float* __restrict__ ln_a,
                             const float* __restrict__ ln_b,
                             float* __restrict__ basesT)   // [M][NNET]
{
    __shared__ __align__(16) unsigned char lds[65536];
    const int n   = blockIdx.x;
    const int tid = threadIdx.x;
    const int l   = tid & 63;
    const int wv  = tid >> 6;      // wave 0..7
    const int lr  = l & 15;
    const int g   = l >> 4;        // k-group
    const int jj  = tid & 255;     // convert-pass column
    const int oo  = tid >> 8;      // convert-pass k-octet (0/1)

    // ---------------- input layer (each wave: its 16 rows, A-layout) ----------------
    const int mrow = wv * 16 + lr;
    const float tval = t[mrow];
    v8s afrag[8];
    {
        float zz[8][8];
        const float* wi = W_in + (size_t)n * HDIM;
        const float* bi = b_in + (size_t)n * HDIM;
        #pragma unroll
        for (int kt = 0; kt < 8; ++kt) {
            const int h0 = kt * 32 + g * 8;
            #pragma unroll
            for (int i = 0; i < 8; ++i)
                zz[kt][i] = tval * wi[h0 + i] + bi[h0 + i];
        }
        float s = 0.f, q = 0.f;
        #pragma unroll
        for (int kt = 0; kt < 8; ++kt)
            #pragma unroll
            for (int i = 0; i < 8; ++i) { float v = zz[kt][i]; s += v; q += v * v; }
        s += __shfl_xor(s, 16); q += __shfl_xor(q, 16);
        s += __shfl_xor(s, 32); q += __shfl_xor(q, 32);
        const float mean = s * (1.f / 256.f);
        const float var  = (q - s * s * (1.f / 256.f)) * (1.f / 255.f); // unbiased
        const float inv  = 1.f / (sqrtf(var) + 1e-6f);                  // eps on std
        const float* la = ln_a + (size_t)n * HDIM;
        const float* lb = ln_b + (size_t)n * HDIM;
        #pragma unroll
        for (int kt = 0; kt < 8; ++kt) {
            const int h0 = kt * 32 + g * 8;
            v8s a;
            #pragma unroll
            for (int i = 0; i < 8; ++i) {
                float v   = zz[kt][i];
                float lnv = (v - mean) * inv * la[h0 + i] + lb[h0 + i];
                a[i] = (short)f2bf(selu_f(v + lnv));
            }
            afrag[kt] = a;
        }
    }
    __syncthreads();   // before first staging into LDS

    unsigned char* const scr = lds + (size_t)wv * 8192;  // inter-layer scratch

    f4 acc[16];

    #pragma unroll 1
    for (int L = 0; L < 3; ++L) {
        const float* Wl = W_h + ((size_t)L * NNET + n) * (HDIM * HDIM);

        const f4 zero = {0.f, 0.f, 0.f, 0.f};
        #pragma unroll
        for (int ct = 0; ct < 16; ++ct) {
            acc[ct] = zero;
            asm volatile("" : "+a"(acc[ct]));   // pin to AGPR side
        }

        // issue sub-tile tt (16 k-rows x 256 j fp32) into fp32 buf tt&1.
        // Wave wv stages rows 2wv, 2wv+1 (1 KB each, 16 B/lane, coalesced).
        auto issue_sub = [&](int tt) {
            unsigned char* dst = lds + (tt & 1) * 16384;
            #pragma unroll
            for (int i = 0; i < 2; ++i) {
                const int r = wv * 2 + i;
                const float* gp = Wl + (size_t)(tt * 16 + r) * HDIM + (l << 2);
                __builtin_amdgcn_global_load_lds(
                    (const __attribute__((address_space(1))) void*)gp,
                    (__attribute__((address_space(3))) void*)(dst + (size_t)r * 1024),
                    16, 0, 0);
            }
        };
        // convert sub-tile tt: fp32 buf (tt&1) -> bf16 tile ((tt>>1)&1),
        // khalf (tt&1). Thread: column jj, k-octet oo. XOR-swizzled v8s write.
        auto convert = [&](int tt) {
            const unsigned char* src = lds + (tt & 1) * 16384;
            v8s pk;
            #pragma unroll
            for (int i = 0; i < 8; ++i) {
                const float v = *(const float*)(src + (size_t)(oo * 8 + i) * 1024 + jj * 4);
                pk[i] = (short)f2bf(v);
            }
            int byte = 32768 + (((tt >> 1) & 1) << 14) + ((tt & 1) << 13)
                     + jj * 32 + oo * 16;
            byte ^= ((jj >> 2) & 7) << 4;
            *(v8s*)(lds + byte) = pk;
        };

        issue_sub(0);
        issue_sub(1);

        #pragma unroll
        for (int s = 0; s < 8; ++s) {
            // ---- sub 2s ----
            asm volatile("s_waitcnt vmcnt(2)" ::: "memory");
            LGKM_BAR();
            convert(2 * s);
            LGKM_BAR();
            if (s < 7) issue_sub(2 * s + 2);
            // ---- sub 2s+1 ----
            if (s < 7) { asm volatile("s_waitcnt vmcnt(2)" ::: "memory"); }
            else       { asm volatile("s_waitcnt vmcnt(0)" ::: "memory"); }
            LGKM_BAR();
            convert(2 * s + 1);
            LGKM_BAR();
            if (s < 7) issue_sub(2 * s + 3);
            // ---- MFMA stage s (K = 32s..32s+31) from bf16 tile s&1 ----
            #pragma unroll
            for (int ct = 0; ct < 16; ++ct) {
                const int jb = ct * 16 + lr;
                int byte = 32768 + ((s & 1) << 14) + ((g >> 1) << 13)
                         + jb * 32 + ((g & 1) << 4);
                byte ^= ((jb >> 2) & 7) << 4;
                const v8s bf = *(const v8s*)(lds + byte);
                acc[ct] = __builtin_amdgcn_mfma_f32_16x16x32_bf16(
                    afrag[s], bf, acc[ct], 0, 0, 0);
            }
        }
        __syncthreads();   // all MFMA reads done; LDS becomes scratch

        // ---------------- epilogue ----------------
        const float* bh = b_h  + ((size_t)L * NNET + n) * HDIM;
        const float* la = ln_a + ((size_t)(L + 1) * NNET + n) * HDIM;
        const float* lb = ln_b + ((size_t)(L + 1) * NNET + n) * HDIM;

        float sums[4] = {0,0,0,0}, sqs[4] = {0,0,0,0};
        #pragma unroll
        for (int ct = 0; ct < 16; ++ct) {
            const float bias = bh[ct * 16 + lr];
            #pragma unroll
            for (int r = 0; r < 4; ++r) {
                float v = acc[ct][r] + bias;
                acc[ct][r] = v;
                sums[r] += v; sqs[r] += v * v;
            }
        }
        #pragma unroll
        for (int r = 0; r < 4; ++r)
            #pragma unroll
            for (int m = 1; m <= 8; m <<= 1) {
                sums[r] += __shfl_xor(sums[r], m);
                sqs[r]  += __shfl_xor(sqs[r],  m);
            }
        float mean[4], inv[4];
        #pragma unroll
        for (int r = 0; r < 4; ++r) {
            mean[r] = sums[r] * (1.f / 256.f);
            float var = (sqs[r] - sums[r] * sums[r] * (1.f / 256.f)) * (1.f / 255.f);
            inv[r] = 1.f / (sqrtf(var) + 1e-6f);
        }

        if (L < 2) {
            // C layout (row=4g+r, col=ct*16+lr) -> scr -> A-fragments
            #pragma unroll
            for (int ct = 0; ct < 16; ++ct) {
                const float a_ = la[ct * 16 + lr], b_ = lb[ct * 16 + lr];
                #pragma unroll
                for (int r = 0; r < 4; ++r) {
                    float v  = acc[ct][r];
                    float sv = selu_f(v + (v - mean[r]) * inv[r] * a_ + b_);
                    const int row  = 4 * g + r;
                    const int byte = (row * 512 + (ct * 16 + lr) * 2) ^ (row << 5);
                    *(unsigned short*)(scr + byte) = f2bf(sv);
                }
            }
            __syncthreads();   // fence ds writes (and the compiler)
            #pragma unroll
            for (int kt = 0; kt < 8; ++kt) {
                const int byte = (lr * 512 + (kt * 32 + g * 8) * 2) ^ (lr << 5);
                afrag[kt] = *(const v8s*)(scr + byte);
            }
            __syncthreads();   // scr reads done before next layer's staging
        } else {
            // fused output layer
            const float* wo = W_out + (size_t)n * HDIM;
            const float bo  = b_out[n];
            float ps[4] = {0,0,0,0};
            #pragma unroll
            for (int ct = 0; ct < 16; ++ct) {
                const float a_ = la[ct * 16 + lr], b_ = lb[ct * 16 + lr];
                const float w_ = wo[ct * 16 + lr];
                #pragma unroll
                for (int r = 0; r < 4; ++r) {
                    float v  = acc[ct][r];
                    float sv = selu_f(v + (v - mean[r]) * inv[r] * a_ + b_);
                    ps[r] += sv * w_;
                }
            }
            #pragma unroll
            for (int r = 0; r < 4; ++r)
                #pragma unroll
                for (int m = 1; m <= 8; m <<= 1)
                    ps[r] += __shfl_xor(ps[r], m);
            #pragma unroll
            for (int r = 0; r < 4; ++r)
                if (lr == r)
                    basesT[(size_t)(wv * 16 + 4 * g + r) * NNET + n] = ps[r] + bo;
        }
    }
}

// score[b, jk] = sum_m x[b,m,jk>>1] * basesT[m][jk] * w[m]
__launch_bounds__(256)
__global__ void score_kernel(const float* __restrict__ x,
                             const float* __restrict__ t,
                             const float* __restrict__ basesT,
                             float* __restrict__ out)
{
    __shared__ float c_lds[M_GRID * 32];
    const int jt  = blockIdx.x;   // 0..4
    const int bt  = blockIdx.y;   // 0..255
    const int tid = threadIdx.x;

    for (int i = tid; i < M_GRID * 32; i += 256) {
        const int m  = i >> 5;
        const int jl = i & 31;
        const float tp = t[m == M_GRID - 1 ? M_GRID - 1 : m + 1];
        const float tm = t[m == 0 ? 0 : m - 1];
        c_lds[i] = basesT[(size_t)m * NNET + jt * 32 + jl] * 0.5f * (tp - tm);
    }
    __syncthreads();

    const int jj = tid & 31;
    const int bs = tid >> 5;
    const int jk = jt * 32 + jj;
    const int b  = bt * 8 + bs;
    const float* xp = x + (size_t)b * (M_GRID * J_FEAT) + (jk >> 1);
    float acc = 0.f;
    #pragma unroll 8
    for (int m = 0; m < M_GRID; ++m)
        acc += xp[(size_t)m * J_FEAT] * c_lds[m * 32 + jj];
    out[(size_t)b * NNET + jk] = acc;
}

extern "C" void kernel_launch(void* const* d_in, const int* in_sizes, int n_in,
                              void* d_out, int out_size, void* d_ws, size_t ws_size,
                              hipStream_t stream)
{
    const float* x     = (const float*)d_in[0];
    const float* t     = (const float*)d_in[1];
    const float* W_in  = (const float*)d_in[2];
    const float* b_in  = (const float*)d_in[3];
    const float* W_h   = (const float*)d_in[4];
    const float* b_h   = (const float*)d_in[5];
    const float* W_out = (const float*)d_in[6];
    const float* b_out = (const float*)d_in[7];
    const float* ln_a  = (const float*)d_in[8];
    const float* ln_b  = (const float*)d_in[9];
    float* basesT = (float*)d_ws;   // 128*160*4 = 80 KiB

    basis_kernel<<<dim3(NNET), dim3(512), 0, stream>>>(
        t, W_in, b_in, W_h, b_h, W_out, b_out, ln_a, ln_b, basesT);
    score_kernel<<<dim3(5, 256), dim3(256), 0, stream>>>(
        x, t, basesT, (float*)d_out);
}